// Round 2
// baseline (1498.705 us; speedup 1.0000x reference)
//
#include <hip/hip_runtime.h>
#include <cstddef>

// Problem constants (from reference)
constexpr int cB = 4, cS = 128, cD = 512, cH = 8, cDK = 64, cF = 2048, cL = 2, cV = 32000;
constexpr int cN = cB * cS; // 512

// ---------------------------------------------------------------------------
// Embedding + positional encoding:  x[n,d] = emb[tok[n],d]*sqrt(D) + pe[n%S,d]
// ---------------------------------------------------------------------------
__global__ __launch_bounds__(256) void embed_k(const float* __restrict__ emb,
                                               const int* __restrict__ tok,
                                               float* __restrict__ X)
{
    int n = blockIdx.x;
    int tid = threadIdx.x;
    int t = tok[n];
    int pos = n & (cS - 1);               // n % S  (pe is tiled over batch)
    const float scale = 22.62741699796952f; // sqrt(512)
    for (int d = tid; d < cD; d += 256) {
        int i2 = d & ~1;                  // 2*(d/2)
        float div = expf(-9.210340371976184f * (float)i2 / (float)cD); // -ln(10000)*2i/D
        float arg = (float)pos * div;
        float p = (d & 1) ? cosf(arg) : sinf(arg);
        X[(long)n * cD + d] = emb[(long)t * cD + d] * scale + p;
    }
}

// ---------------------------------------------------------------------------
// LayerNorm over D=512, one block per row, 256 threads (2 elems/thread)
// ---------------------------------------------------------------------------
__global__ __launch_bounds__(256) void ln_k(const float* __restrict__ X,
                                            const float* __restrict__ g,
                                            const float* __restrict__ bta,
                                            float* __restrict__ Y)
{
    __shared__ float red[256];
    int row = blockIdx.x, tid = threadIdx.x;
    const float* x = X + (long)row * cD;
    float v0 = x[tid], v1 = x[tid + 256];

    red[tid] = v0 + v1;
    __syncthreads();
    for (int st = 128; st > 0; st >>= 1) { if (tid < st) red[tid] += red[tid + st]; __syncthreads(); }
    float mu = red[0] * (1.0f / (float)cD);
    __syncthreads();

    float d0 = v0 - mu, d1 = v1 - mu;
    red[tid] = d0 * d0 + d1 * d1;
    __syncthreads();
    for (int st = 128; st > 0; st >>= 1) { if (tid < st) red[tid] += red[tid + st]; __syncthreads(); }
    float var = red[0] * (1.0f / (float)cD);
    float rs = rsqrtf(var + 1e-5f);

    Y[(long)row * cD + tid]       = g[tid]       * d0 * rs + bta[tid];
    Y[(long)row * cD + tid + 256] = g[tid + 256] * d1 * rs + bta[tid + 256];
}

// ---------------------------------------------------------------------------
// Generic tiled fp32 GEMM:  C = act(A[M,K] @ B[K,N] + bias) + res
// 256 threads (16x16), each computes TR x TC outputs (strided layout ->
// conflict-free LDS reads, coalesced C stores).
// blockIdx.z batches independent B/C (QKV, cross-KV) via strides.
// ---------------------------------------------------------------------------
template <int TR, int TC>
__global__ __launch_bounds__(256) void gemm_k(const float* __restrict__ A,
                                              const float* __restrict__ B0,
                                              const float* __restrict__ bias0,
                                              const float* res0, float* C0,
                                              int M, int Nc, int K, int relu,
                                              long bStride, long cStride)
{
    constexpr int BM = TR * 16, BN = TC * 16;
    __shared__ float As[16][BM + 4];
    __shared__ float Bs[16][BN];

    const float* Bm = B0 + (long)blockIdx.z * bStride;
    float* C = C0 + (long)blockIdx.z * cStride;

    int tid = threadIdx.x;
    int tx = tid & 15, ty = tid >> 4;
    int n0 = blockIdx.x * BN, m0 = blockIdx.y * BM;

    float acc[TR][TC];
#pragma unroll
    for (int r = 0; r < TR; r++)
#pragma unroll
        for (int c = 0; c < TC; c++) acc[r][c] = 0.0f;

    for (int k0 = 0; k0 < K; k0 += 16) {
#pragma unroll
        for (int i = 0; i < TR; i++) {           // A tile: BM x 16
            int lin = tid + i * 256;
            int m = lin >> 4, kk = lin & 15;
            As[kk][m] = A[(long)(m0 + m) * K + k0 + kk];
        }
#pragma unroll
        for (int i = 0; i < TC; i++) {           // B tile: 16 x BN
            int lin = tid + i * 256;
            int kk = lin / BN, n = lin % BN;
            Bs[kk][n] = Bm[(long)(k0 + kk) * Nc + n0 + n];
        }
        __syncthreads();
#pragma unroll
        for (int kk = 0; kk < 16; kk++) {
            float a[TR], b[TC];
#pragma unroll
            for (int r = 0; r < TR; r++) a[r] = As[kk][ty + r * 16];
#pragma unroll
            for (int c = 0; c < TC; c++) b[c] = Bs[kk][tx + c * 16];
#pragma unroll
            for (int r = 0; r < TR; r++)
#pragma unroll
                for (int c = 0; c < TC; c++) acc[r][c] += a[r] * b[c];
        }
        __syncthreads();
    }

#pragma unroll
    for (int r = 0; r < TR; r++) {
        int row = m0 + ty + r * 16;
#pragma unroll
        for (int c = 0; c < TC; c++) {
            int col = n0 + tx + c * 16;
            float v = acc[r][c];
            if (bias0) v += bias0[col];
            if (res0)  v += res0[(long)row * Nc + col];
            if (relu)  v = fmaxf(v, 0.0f);
            C[(long)row * Nc + col] = v;
        }
    }
}

// ---------------------------------------------------------------------------
// Attention, one block per (dst pos, head, batch). 128 threads.
// q,k,v,o layout: [N, H*DK] row-major (h*64+d).
// score = exp(clip(q.k/8, -10, 10)); causal masks src>dst.
// o[dst] = sum_src s*v[src] / sum_src s    (exactly the reference formula)
// ---------------------------------------------------------------------------
__global__ __launch_bounds__(128) void attn_k(const float* __restrict__ Q,
                                              const float* __restrict__ Km,
                                              const float* __restrict__ Vm,
                                              float* __restrict__ O, int causal)
{
    __shared__ float ks[cDK][cS + 1];  // transposed [d][src], +1 pad: conflict-free
    __shared__ float qs[cDK];
    __shared__ float ss[cS];
    __shared__ float red[cS];
    __shared__ float pv[2][cDK];

    int tid = threadIdx.x;
    int dst = blockIdx.x;            // 0..S-1
    int h = blockIdx.y, b = blockIdx.z;
    long base = ((long)b * cS) * (cH * cDK) + h * cDK;

    if (tid < cDK) qs[tid] = Q[((long)(b * cS + dst)) * (cH * cDK) + h * cDK + tid];
    for (int i = 0; i < (cS * cDK) / 128; i++) {
        int lin = tid + i * 128;
        int src = lin >> 6, d = lin & 63;
        ks[d][src] = Km[base + (long)src * (cH * cDK) + d];
    }
    __syncthreads();

    // one src per thread
    float dot = 0.0f;
#pragma unroll
    for (int d = 0; d < cDK; d++) dot += ks[d][tid] * qs[d];
    dot *= 0.125f;                              // 1/sqrt(64)
    dot = fminf(fmaxf(dot, -10.0f), 10.0f);
    float s = expf(dot);
    if (causal && tid > dst) s = 0.0f;          // edge i<=j only
    ss[tid] = s;
    red[tid] = s;
    __syncthreads();
    for (int st = 64; st > 0; st >>= 1) { if (tid < st) red[tid] += red[tid + st]; __syncthreads(); }
    float z = red[0];

    // weighted V: wave0 does src 0..63, wave1 src 64..127
    int half = tid >> 6, d = tid & 63;
    float acc = 0.0f;
    for (int src = half * 64; src < half * 64 + 64; src++)
        acc += ss[src] * Vm[base + (long)src * (cH * cDK) + d];
    pv[half][d] = acc;
    __syncthreads();

    if (tid < cDK)
        O[((long)(b * cS + dst)) * (cH * cDK) + h * cDK + tid] = (pv[0][tid] + pv[1][tid]) / z;
}

// ---------------------------------------------------------------------------
// In-place row log_softmax over V=32000, one block per row
// ---------------------------------------------------------------------------
__global__ __launch_bounds__(256) void lsm_k(float* __restrict__ X)
{
    __shared__ float red[256];
    int row = blockIdx.x, tid = threadIdx.x;
    float* x = X + (long)row * cV;

    float m = -1e30f;
    for (int i = tid; i < cV; i += 256) m = fmaxf(m, x[i]);
    red[tid] = m;
    __syncthreads();
    for (int st = 128; st > 0; st >>= 1) { if (tid < st) red[tid] = fmaxf(red[tid], red[tid + st]); __syncthreads(); }
    m = red[0];
    __syncthreads();

    float ssum = 0.0f;
    for (int i = tid; i < cV; i += 256) ssum += expf(x[i] - m);
    red[tid] = ssum;
    __syncthreads();
    for (int st = 128; st > 0; st >>= 1) { if (tid < st) red[tid] += red[tid + st]; __syncthreads(); }
    float lse = m + logf(red[0]);

    for (int i = tid; i < cV; i += 256) x[i] = x[i] - lse;
}

// ---------------------------------------------------------------------------
extern "C" void kernel_launch(void* const* d_in, const int* in_sizes, int n_in,
                              void* d_out, int out_size, void* d_ws, size_t ws_size,
                              hipStream_t stream)
{
    const float* src_emb  = (const float*)d_in[0];   // [V,D]
    const float* tgt_emb  = (const float*)d_in[1];   // [V,D]
    const float* enc_Wqkv = (const float*)d_in[2];   // [L,3,D,D]
    const float* enc_Wo   = (const float*)d_in[3];   // [L,D,D]
    const float* enc_ln1  = (const float*)d_in[4];   // [L,2,D]
    const float* enc_W1   = (const float*)d_in[5];   // [L,D,F]
    const float* enc_b1   = (const float*)d_in[6];   // [L,F]
    const float* enc_W2   = (const float*)d_in[7];   // [L,F,D]
    const float* enc_b2   = (const float*)d_in[8];   // [L,D]
    const float* enc_ln2  = (const float*)d_in[9];   // [L,2,D]
    const float* enc_lnf  = (const float*)d_in[10];  // [2,D]
    const float* dec_Wqkv = (const float*)d_in[11];  // [L,3,D,D]
    const float* dec_Wo   = (const float*)d_in[12];  // [L,D,D]
    const float* dec_ln1  = (const float*)d_in[13];  // [L,2,D]
    const float* dec_cWq  = (const float*)d_in[14];  // [L,D,D]
    const float* dec_cWkv = (const float*)d_in[15];  // [L,2,D,D]
    const float* dec_cWo  = (const float*)d_in[16];  // [L,D,D]
    const float* dec_ln2  = (const float*)d_in[17];  // [L,2,D]
    const float* dec_W1   = (const float*)d_in[18];  // [L,D,F]
    const float* dec_b1   = (const float*)d_in[19];  // [L,F]
    const float* dec_W2   = (const float*)d_in[20];  // [L,F,D]
    const float* dec_b2   = (const float*)d_in[21];  // [L,D]
    const float* dec_ln3  = (const float*)d_in[22];  // [L,2,D]
    const float* dec_lnf  = (const float*)d_in[23];  // [2,D]
    const float* gen_W    = (const float*)d_in[24];  // [D,V]
    const float* gen_b    = (const float*)d_in[25];  // [V]
    const int* src_tok    = (const int*)d_in[26];    // [B,S]
    const int* tgt_tok    = (const int*)d_in[27];    // [B,S]
    // d_in[28..33] edge lists: structure is fixed (full / causal per sentence) -> unused

    const long ND = (long)cN * cD;
    float* ws = (float*)d_ws;
    float* x_e     = ws;             // [N,D]
    float* x_d     = x_e + ND;       // [N,D]
    float* xn      = x_d + ND;       // [N,D]
    float* qb      = xn + ND;        // [N,D]
    float* kb      = qb + ND;        // [N,D]  (qb,kb,vb contiguous for z-batch)
    float* vb      = kb + ND;        // [N,D]
    float* ob      = vb + ND;        // [N,D]
    float* enc_out = ob + ND;        // [N,D]
    float* hb      = enc_out + ND;   // [N,F]

    const long DD = (long)cD * cD;
    dim3 gDD(cD / 32, cN / 32);        // <2,2> tiles for D x D GEMMs
    dim3 gF1(cF / 64, cN / 64);        // <4,4> for FFN up
    dim3 gF2(cD / 32, cN / 32);        // <2,2> for FFN down
    dim3 gAttn(cS, cH, cB);

    // ---- embeddings ----
    embed_k<<<cN, 256, 0, stream>>>(src_emb, src_tok, x_e);
    embed_k<<<cN, 256, 0, stream>>>(tgt_emb, tgt_tok, x_d);

    // ---- encoder ----
    for (int l = 0; l < cL; l++) {
        ln_k<<<cN, 256, 0, stream>>>(x_e, enc_ln1 + (long)(l * 2) * cD,
                                     enc_ln1 + (long)(l * 2 + 1) * cD, xn);
        gemm_k<2, 2><<<dim3(cD / 32, cN / 32, 3), 256, 0, stream>>>(
            xn, enc_Wqkv + (long)l * 3 * DD, nullptr, nullptr, qb,
            cN, cD, cD, 0, DD, ND);
        attn_k<<<gAttn, 128, 0, stream>>>(qb, kb, vb, ob, 0);
        gemm_k<2, 2><<<gDD, 256, 0, stream>>>(ob, enc_Wo + (long)l * DD, nullptr,
                                              x_e, x_e, cN, cD, cD, 0, 0, 0);
        ln_k<<<cN, 256, 0, stream>>>(x_e, enc_ln2 + (long)(l * 2) * cD,
                                     enc_ln2 + (long)(l * 2 + 1) * cD, xn);
        gemm_k<4, 4><<<gF1, 256, 0, stream>>>(xn, enc_W1 + (long)l * cD * cF,
                                              enc_b1 + (long)l * cF, nullptr, hb,
                                              cN, cF, cD, 1, 0, 0);
        gemm_k<2, 2><<<gF2, 256, 0, stream>>>(hb, enc_W2 + (long)l * cF * cD,
                                              enc_b2 + (long)l * cD, x_e, x_e,
                                              cN, cD, cF, 0, 0, 0);
    }
    ln_k<<<cN, 256, 0, stream>>>(x_e, enc_lnf, enc_lnf + cD, enc_out);

    // ---- decoder ----
    for (int l = 0; l < cL; l++) {
        // self-attention (causal)
        ln_k<<<cN, 256, 0, stream>>>(x_d, dec_ln1 + (long)(l * 2) * cD,
                                     dec_ln1 + (long)(l * 2 + 1) * cD, xn);
        gemm_k<2, 2><<<dim3(cD / 32, cN / 32, 3), 256, 0, stream>>>(
            xn, dec_Wqkv + (long)l * 3 * DD, nullptr, nullptr, qb,
            cN, cD, cD, 0, DD, ND);
        attn_k<<<gAttn, 128, 0, stream>>>(qb, kb, vb, ob, 1);
        gemm_k<2, 2><<<gDD, 256, 0, stream>>>(ob, dec_Wo + (long)l * DD, nullptr,
                                              x_d, x_d, cN, cD, cD, 0, 0, 0);
        // cross-attention (full, K/V from encoder output)
        ln_k<<<cN, 256, 0, stream>>>(x_d, dec_ln2 + (long)(l * 2) * cD,
                                     dec_ln2 + (long)(l * 2 + 1) * cD, xn);
        gemm_k<2, 2><<<gDD, 256, 0, stream>>>(xn, dec_cWq + (long)l * DD, nullptr,
                                              nullptr, qb, cN, cD, cD, 0, 0, 0);
        gemm_k<2, 2><<<dim3(cD / 32, cN / 32, 2), 256, 0, stream>>>(
            enc_out, dec_cWkv + (long)l * 2 * DD, nullptr, nullptr, kb,
            cN, cD, cD, 0, DD, ND);
        attn_k<<<gAttn, 128, 0, stream>>>(qb, kb, vb, ob, 0);
        gemm_k<2, 2><<<gDD, 256, 0, stream>>>(ob, dec_cWo + (long)l * DD, nullptr,
                                              x_d, x_d, cN, cD, cD, 0, 0, 0);
        // FFN
        ln_k<<<cN, 256, 0, stream>>>(x_d, dec_ln3 + (long)(l * 2) * cD,
                                     dec_ln3 + (long)(l * 2 + 1) * cD, xn);
        gemm_k<4, 4><<<gF1, 256, 0, stream>>>(xn, dec_W1 + (long)l * cD * cF,
                                              dec_b1 + (long)l * cF, nullptr, hb,
                                              cN, cF, cD, 1, 0, 0);
        gemm_k<2, 2><<<gF2, 256, 0, stream>>>(hb, dec_W2 + (long)l * cF * cD,
                                              dec_b2 + (long)l * cD, x_d, x_d,
                                              cN, cD, cF, 0, 0, 0);
    }
    ln_k<<<cN, 256, 0, stream>>>(x_d, dec_lnf, dec_lnf + cD, xn);

    // ---- generator + log_softmax ----
    gemm_k<8, 8><<<dim3(cV / 128, cN / 128), 256, 0, stream>>>(
        xn, gen_W, gen_b, nullptr, (float*)d_out, cN, cV, cD, 0, 0, 0);
    lsm_k<<<cN, 256, 0, stream>>>((float*)d_out);
}

// Round 3
// 597.943 us; speedup vs baseline: 2.5064x; 2.5064x over previous
//
#include <hip/hip_runtime.h>
#include <cstddef>

// Problem constants (from reference)
constexpr int cB = 4, cS = 128, cD = 512, cH = 8, cDK = 64, cF = 2048, cL = 2, cV = 32000;
constexpr int cN = cB * cS; // 512

typedef __attribute__((ext_vector_type(8))) short short8;   // 8 x bf16 (MFMA frag)
typedef __attribute__((ext_vector_type(4))) float f32x4;    // MFMA acc

__device__ __forceinline__ short f2bf(float x) {            // RNE fp32->bf16
    unsigned u = __builtin_bit_cast(unsigned, x);
    unsigned r = (u + 0x7fffu + ((u >> 16) & 1u)) >> 16;
    return (short)r;
}

// ---------------------------------------------------------------------------
// Embedding + positional encoding (fp32 residual stream)
// ---------------------------------------------------------------------------
__global__ __launch_bounds__(256) void embed_k(const float* __restrict__ emb,
                                               const int* __restrict__ tok,
                                               float* __restrict__ X)
{
    int n = blockIdx.x;
    int tid = threadIdx.x;
    int t = tok[n];
    int pos = n & (cS - 1);
    const float scale = 22.62741699796952f; // sqrt(512)
    for (int d = tid; d < cD; d += 256) {
        int i2 = d & ~1;
        float div = expf(-9.210340371976184f * (float)i2 / (float)cD);
        float arg = (float)pos * div;
        float p = (d & 1) ? cosf(arg) : sinf(arg);
        X[(long)n * cD + d] = emb[(long)t * cD + d] * scale + p;
    }
}

// ---------------------------------------------------------------------------
// LayerNorm over D=512 -> bf16 output (only GEMMs consume LN outputs)
// ---------------------------------------------------------------------------
__global__ __launch_bounds__(256) void ln_k(const float* __restrict__ X,
                                            const float* __restrict__ g,
                                            const float* __restrict__ bta,
                                            short* __restrict__ Yb)
{
    __shared__ float red[256];
    int row = blockIdx.x, tid = threadIdx.x;
    const float* x = X + (long)row * cD;
    float v0 = x[tid], v1 = x[tid + 256];

    red[tid] = v0 + v1;
    __syncthreads();
    for (int st = 128; st > 0; st >>= 1) { if (tid < st) red[tid] += red[tid + st]; __syncthreads(); }
    float mu = red[0] * (1.0f / (float)cD);
    __syncthreads();

    float d0 = v0 - mu, d1 = v1 - mu;
    red[tid] = d0 * d0 + d1 * d1;
    __syncthreads();
    for (int st = 128; st > 0; st >>= 1) { if (tid < st) red[tid] += red[tid + st]; __syncthreads(); }
    float var = red[0] * (1.0f / (float)cD);
    float rs = rsqrtf(var + 1e-5f);

    Yb[(long)row * cD + tid]       = f2bf(g[tid]       * d0 * rs + bta[tid]);
    Yb[(long)row * cD + tid + 256] = f2bf(g[tid + 256] * d1 * rs + bta[tid + 256]);
}

// ---------------------------------------------------------------------------
// Transpose-convert weights: src fp32 [K][N] -> dst bf16 [N][K], z-batched.
// 32x32 LDS tile keeps both sides coalesced.
// ---------------------------------------------------------------------------
__global__ __launch_bounds__(256) void tconv_k(const float* __restrict__ src,
                                               short* __restrict__ dst,
                                               int K, int N)
{
    __shared__ float t[32][33];
    long zs = (long)K * N;
    const float* s = src + (long)blockIdx.z * zs;
    short* d = dst + (long)blockIdx.z * zs;
    int k0 = blockIdx.y * 32, n0 = blockIdx.x * 32;
    int tid = threadIdx.x;
#pragma unroll
    for (int i = 0; i < 4; i++) {
        int lin = tid + i * 256, r = lin >> 5, c = lin & 31;
        t[r][c] = s[(long)(k0 + r) * N + n0 + c];
    }
    __syncthreads();
#pragma unroll
    for (int i = 0; i < 4; i++) {
        int lin = tid + i * 256, r = lin >> 5, c = lin & 31;  // r = n, c = k
        d[(long)(n0 + r) * K + k0 + c] = f2bf(t[c][r]);
    }
}

// ---------------------------------------------------------------------------
// bf16 MFMA GEMM:  C[M,N] = act(A[M,K] @ B[K,N] + bias) + res
// A bf16 row-major [M][K]; Bt bf16 TRANSPOSED [N][K].
// 256 threads = 4 waves in 2x2; wave tile (MR*16) x (NR*16); BK=32.
// Reg-staged prefetch: next tile's global loads issue before current MFMAs.
// LDS pitch BK+8 -> frag ds_read_b128 is 2-way max (free, m136).
// swz: XCD-friendly remap so row-tiles sharing a B panel are dispatch-adjacent.
// ---------------------------------------------------------------------------
template <int MR, int NR>
__global__ __launch_bounds__(256) void gemm_bf16_k(
    const short* __restrict__ A, const short* __restrict__ Bt,
    const float* __restrict__ bias, const float* __restrict__ res,
    float* __restrict__ C, short* __restrict__ Cb,
    int N, int K, int relu, long btStride, long cStride, int swz)
{
    constexpr int BM = MR * 32, BN = NR * 32, BK = 32, PITCH = BK + 8;
    constexpr int AL = (BM * BK) / (256 * 8);   // 16B loads/thread for A tile
    constexpr int BL = (BN * BK) / (256 * 8);
    static_assert(AL >= 1 && BL >= 1, "tile too small");
    __shared__ short As[BM * PITCH];
    __shared__ short Bs[BN * PITCH];

    int bx = blockIdx.x, by = blockIdx.y;
    if (swz) {  // group gridDim.y row-tiles of one col-tile onto one XCD
        int nb = gridDim.x * gridDim.y;
        int bid = by * gridDim.x + bx;
        int w = (bid & 7) * (nb >> 3) + (bid >> 3);
        by = w % gridDim.y; bx = w / gridDim.y;
    }

    const short* Bm = Bt + (long)blockIdx.z * btStride;
    int tid = threadIdx.x;
    int lane = tid & 63, wid = tid >> 6;
    int wr = wid >> 1, wc = wid & 1;
    int m0 = by * BM, n0 = bx * BN;
    int lrow = lane & 15, koff = (lane >> 4) * 8;

    f32x4 acc[MR][NR];
#pragma unroll
    for (int m = 0; m < MR; m++)
#pragma unroll
        for (int n = 0; n < NR; n++) acc[m][n] = f32x4{0.f, 0.f, 0.f, 0.f};

    short8 ra[AL], rb[BL];
    auto loadT = [&](int k0) {
#pragma unroll
        for (int i = 0; i < AL; i++) {
            int lin = tid + i * 256, r = lin >> 2, c8 = lin & 3;
            ra[i] = *(const short8*)&A[(long)(m0 + r) * K + k0 + c8 * 8];
        }
#pragma unroll
        for (int i = 0; i < BL; i++) {
            int lin = tid + i * 256, r = lin >> 2, c8 = lin & 3;
            rb[i] = *(const short8*)&Bm[(long)(n0 + r) * K + k0 + c8 * 8];
        }
    };

    loadT(0);
    for (int k0 = 0; k0 < K; k0 += BK) {
        __syncthreads();   // prior frag reads done -> safe to overwrite LDS
#pragma unroll
        for (int i = 0; i < AL; i++) {
            int lin = tid + i * 256, r = lin >> 2, c8 = lin & 3;
            *(short8*)&As[r * PITCH + c8 * 8] = ra[i];
        }
#pragma unroll
        for (int i = 0; i < BL; i++) {
            int lin = tid + i * 256, r = lin >> 2, c8 = lin & 3;
            *(short8*)&Bs[r * PITCH + c8 * 8] = rb[i];
        }
        __syncthreads();
        if (k0 + BK < K) loadT(k0 + BK);   // prefetch overlaps MFMAs below

        short8 a[MR], b[NR];
#pragma unroll
        for (int m = 0; m < MR; m++)
            a[m] = *(const short8*)&As[(wr * MR * 16 + m * 16 + lrow) * PITCH + koff];
#pragma unroll
        for (int n = 0; n < NR; n++)
            b[n] = *(const short8*)&Bs[(wc * NR * 16 + n * 16 + lrow) * PITCH + koff];
#pragma unroll
        for (int m = 0; m < MR; m++)
#pragma unroll
            for (int n = 0; n < NR; n++)
                acc[m][n] = __builtin_amdgcn_mfma_f32_16x16x32_bf16(a[m], b[n], acc[m][n], 0, 0, 0);
    }

    // epilogue: C/D layout col=lane&15, row=(lane>>4)*4+j  [m89]
#pragma unroll
    for (int m = 0; m < MR; m++) {
        int rbase = m0 + wr * MR * 16 + m * 16 + (lane >> 4) * 4;
#pragma unroll
        for (int n = 0; n < NR; n++) {
            int col = n0 + wc * NR * 16 + n * 16 + (lane & 15);
            float bv = bias ? bias[col] : 0.f;
#pragma unroll
            for (int j = 0; j < 4; j++) {
                long row = rbase + j;
                float v = acc[m][n][j] + bv;
                if (res)  v += res[row * N + col];
                if (relu) v = fmaxf(v, 0.f);
                long off = row * N + col + (long)blockIdx.z * cStride;
                if (C)  C[off] = v;
                if (Cb) Cb[off] = f2bf(v);
            }
        }
    }
}

// ---------------------------------------------------------------------------
// Attention (unchanged math, bf16 output for the O-projection GEMM)
// ---------------------------------------------------------------------------
__global__ __launch_bounds__(128) void attn_k(const float* __restrict__ Q,
                                              const float* __restrict__ Km,
                                              const float* __restrict__ Vm,
                                              short* __restrict__ O, int causal)
{
    __shared__ float ks[cDK][cS + 1];
    __shared__ float qs[cDK];
    __shared__ float ss[cS];
    __shared__ float red[cS];
    __shared__ float pv[2][cDK];

    int tid = threadIdx.x;
    int dst = blockIdx.x;
    int h = blockIdx.y, b = blockIdx.z;
    long base = ((long)b * cS) * (cH * cDK) + h * cDK;

    if (tid < cDK) qs[tid] = Q[((long)(b * cS + dst)) * (cH * cDK) + h * cDK + tid];
    for (int i = 0; i < (cS * cDK) / 128; i++) {
        int lin = tid + i * 128;
        int src = lin >> 6, d = lin & 63;
        ks[d][src] = Km[base + (long)src * (cH * cDK) + d];
    }
    __syncthreads();

    float dot = 0.0f;
#pragma unroll
    for (int d = 0; d < cDK; d++) dot += ks[d][tid] * qs[d];
    dot *= 0.125f;
    dot = fminf(fmaxf(dot, -10.0f), 10.0f);
    float s = expf(dot);
    if (causal && tid > dst) s = 0.0f;
    ss[tid] = s;
    red[tid] = s;
    __syncthreads();
    for (int st = 64; st > 0; st >>= 1) { if (tid < st) red[tid] += red[tid + st]; __syncthreads(); }
    float z = red[0];

    int half = tid >> 6, d = tid & 63;
    float acc = 0.0f;
    for (int src = half * 64; src < half * 64 + 64; src++)
        acc += ss[src] * Vm[base + (long)src * (cH * cDK) + d];
    pv[half][d] = acc;
    __syncthreads();

    if (tid < cDK)
        O[((long)(b * cS + dst)) * (cH * cDK) + h * cDK + tid] = f2bf((pv[0][tid] + pv[1][tid]) / z);
}

// ---------------------------------------------------------------------------
// In-place row log_softmax over V=32000, float4-vectorized
// ---------------------------------------------------------------------------
__global__ __launch_bounds__(256) void lsm_k(float* __restrict__ X)
{
    __shared__ float red[256];
    int row = blockIdx.x, tid = threadIdx.x;
    float* x = X + (long)row * cV;
    f32x4* x4 = (f32x4*)x;
    constexpr int NV = cV / 4;

    float m = -1e30f;
    for (int i = tid; i < NV; i += 256) {
        f32x4 v = x4[i];
        m = fmaxf(m, fmaxf(fmaxf(v[0], v[1]), fmaxf(v[2], v[3])));
    }
    red[tid] = m;
    __syncthreads();
    for (int st = 128; st > 0; st >>= 1) { if (tid < st) red[tid] = fmaxf(red[tid], red[tid + st]); __syncthreads(); }
    m = red[0];
    __syncthreads();

    float ssum = 0.0f;
    for (int i = tid; i < NV; i += 256) {
        f32x4 v = x4[i];
        ssum += expf(v[0] - m) + expf(v[1] - m) + expf(v[2] - m) + expf(v[3] - m);
    }
    red[tid] = ssum;
    __syncthreads();
    for (int st = 128; st > 0; st >>= 1) { if (tid < st) red[tid] += red[tid + st]; __syncthreads(); }
    float lse = m + logf(red[0]);

    for (int i = tid; i < NV; i += 256) {
        f32x4 v = x4[i];
        v[0] -= lse; v[1] -= lse; v[2] -= lse; v[3] -= lse;
        x4[i] = v;
    }
}

// ---------------------------------------------------------------------------
extern "C" void kernel_launch(void* const* d_in, const int* in_sizes, int n_in,
                              void* d_out, int out_size, void* d_ws, size_t ws_size,
                              hipStream_t stream)
{
    const float* src_emb  = (const float*)d_in[0];
    const float* tgt_emb  = (const float*)d_in[1];
    const float* enc_Wqkv = (const float*)d_in[2];
    const float* enc_Wo   = (const float*)d_in[3];
    const float* enc_ln1  = (const float*)d_in[4];
    const float* enc_W1   = (const float*)d_in[5];
    const float* enc_b1   = (const float*)d_in[6];
    const float* enc_W2   = (const float*)d_in[7];
    const float* enc_b2   = (const float*)d_in[8];
    const float* enc_ln2  = (const float*)d_in[9];
    const float* enc_lnf  = (const float*)d_in[10];
    const float* dec_Wqkv = (const float*)d_in[11];
    const float* dec_Wo   = (const float*)d_in[12];
    const float* dec_ln1  = (const float*)d_in[13];
    const float* dec_cWq  = (const float*)d_in[14];
    const float* dec_cWkv = (const float*)d_in[15];
    const float* dec_cWo  = (const float*)d_in[16];
    const float* dec_ln2  = (const float*)d_in[17];
    const float* dec_W1   = (const float*)d_in[18];
    const float* dec_b1   = (const float*)d_in[19];
    const float* dec_W2   = (const float*)d_in[20];
    const float* dec_b2   = (const float*)d_in[21];
    const float* dec_ln3  = (const float*)d_in[22];
    const float* dec_lnf  = (const float*)d_in[23];
    const float* gen_W    = (const float*)d_in[24];
    const float* gen_b    = (const float*)d_in[25];
    const int* src_tok    = (const int*)d_in[26];
    const int* tgt_tok    = (const int*)d_in[27];
    // edge lists (28..33): fixed structure (full / causal) -> unused

    const long ND = (long)cN * cD;          // 262144
    const long DD = (long)cD * cD;          // 262144
    const long DF = (long)cD * cF;          // 1048576

    // fp32 region: residual streams + q/k/v
    float* f  = (float*)d_ws;
    float* x_e = f;
    float* x_d = x_e + ND;
    float* qb  = x_d + ND;
    float* kb  = qb + ND;   // q,k,v contiguous (z-batched GEMM output)
    float* vb  = kb + ND;

    // bf16 region
    short* s = (short*)(vb + ND);
    short* xn_bf  = s;             // [N,D]
    short* ob_bf  = xn_bf + ND;    // [N,D]
    short* hb_bf  = ob_bf + ND;    // [N,F]
    short* enc_bf = hb_bf + (long)cN * cF;  // [N,D]
    // transposed bf16 weights
    short* w = enc_bf + ND;
    short* enc_wqkv_t = w;                      // 6*DD
    short* enc_wo_t   = enc_wqkv_t + 6 * DD;    // 2*DD
    short* enc_w1_t   = enc_wo_t   + 2 * DD;    // 2*DF
    short* enc_w2_t   = enc_w1_t   + 2 * DF;    // 2*DF
    short* dec_wqkv_t = enc_w2_t   + 2 * DF;    // 6*DD
    short* dec_wo_t   = dec_wqkv_t + 6 * DD;    // 2*DD
    short* dec_cwq_t  = dec_wo_t   + 2 * DD;    // 2*DD
    short* dec_cwkv_t = dec_cwq_t  + 2 * DD;    // 4*DD
    short* dec_cwo_t  = dec_cwkv_t + 4 * DD;    // 2*DD
    short* dec_w1_t   = dec_cwo_t  + 2 * DD;    // 2*DF
    short* dec_w2_t   = dec_w1_t   + 2 * DF;    // 2*DF
    short* gen_t      = dec_w2_t   + 2 * DF;    // D*V

    // ---- weight transpose-converts (once per launch) ----
    auto T = [&](const float* sp, short* dp, int K2, int N2, int Z) {
        tconv_k<<<dim3(N2 / 32, K2 / 32, Z), 256, 0, stream>>>(sp, dp, K2, N2);
    };
    T(enc_Wqkv, enc_wqkv_t, cD, cD, 6);
    T(enc_Wo,   enc_wo_t,   cD, cD, 2);
    T(enc_W1,   enc_w1_t,   cD, cF, 2);
    T(enc_W2,   enc_w2_t,   cF, cD, 2);
    T(dec_Wqkv, dec_wqkv_t, cD, cD, 6);
    T(dec_Wo,   dec_wo_t,   cD, cD, 2);
    T(dec_cWq,  dec_cwq_t,  cD, cD, 2);
    T(dec_cWkv, dec_cwkv_t, cD, cD, 4);
    T(dec_cWo,  dec_cwo_t,  cD, cD, 2);
    T(dec_W1,   dec_w1_t,   cD, cF, 2);
    T(dec_W2,   dec_w2_t,   cF, cD, 2);
    T(gen_W,    gen_t,      cD, cV, 1);

    dim3 gDD(cD / 64, cN / 64);     // 8x8
    dim3 gF1(cF / 64, cN / 64);     // 32x8
    dim3 gAttn(cS, cH, cB);

    // ---- embeddings ----
    embed_k<<<cN, 256, 0, stream>>>(src_emb, src_tok, x_e);
    embed_k<<<cN, 256, 0, stream>>>(tgt_emb, tgt_tok, x_d);

    // ---- encoder ----
    for (int l = 0; l < cL; l++) {
        ln_k<<<cN, 256, 0, stream>>>(x_e, enc_ln1 + (long)(l * 2) * cD,
                                     enc_ln1 + (long)(l * 2 + 1) * cD, xn_bf);
        gemm_bf16_k<2, 2><<<dim3(cD / 64, cN / 64, 3), 256, 0, stream>>>(
            xn_bf, enc_wqkv_t + (long)l * 3 * DD, nullptr, nullptr, qb, nullptr,
            cD, cD, 0, DD, ND, 0);
        attn_k<<<gAttn, 128, 0, stream>>>(qb, kb, vb, ob_bf, 0);
        gemm_bf16_k<2, 2><<<gDD, 256, 0, stream>>>(
            ob_bf, enc_wo_t + (long)l * DD, nullptr, x_e, x_e, nullptr,
            cD, cD, 0, 0, 0, 0);
        ln_k<<<cN, 256, 0, stream>>>(x_e, enc_ln2 + (long)(l * 2) * cD,
                                     enc_ln2 + (long)(l * 2 + 1) * cD, xn_bf);
        gemm_bf16_k<2, 2><<<gF1, 256, 0, stream>>>(
            xn_bf, enc_w1_t + (long)l * DF, enc_b1 + (long)l * cF, nullptr,
            nullptr, hb_bf, cF, cD, 1, 0, 0, 0);
        gemm_bf16_k<2, 2><<<gDD, 256, 0, stream>>>(
            hb_bf, enc_w2_t + (long)l * DF, enc_b2 + (long)l * cD, x_e, x_e,
            nullptr, cD, cF, 0, 0, 0, 0);
    }
    ln_k<<<cN, 256, 0, stream>>>(x_e, enc_lnf, enc_lnf + cD, enc_bf);

    // ---- decoder ----
    for (int l = 0; l < cL; l++) {
        ln_k<<<cN, 256, 0, stream>>>(x_d, dec_ln1 + (long)(l * 2) * cD,
                                     dec_ln1 + (long)(l * 2 + 1) * cD, xn_bf);
        gemm_bf16_k<2, 2><<<dim3(cD / 64, cN / 64, 3), 256, 0, stream>>>(
            xn_bf, dec_wqkv_t + (long)l * 3 * DD, nullptr, nullptr, qb, nullptr,
            cD, cD, 0, DD, ND, 0);
        attn_k<<<gAttn, 128, 0, stream>>>(qb, kb, vb, ob_bf, 1);
        gemm_bf16_k<2, 2><<<gDD, 256, 0, stream>>>(
            ob_bf, dec_wo_t + (long)l * DD, nullptr, x_d, x_d, nullptr,
            cD, cD, 0, 0, 0, 0);

        ln_k<<<cN, 256, 0, stream>>>(x_d, dec_ln2 + (long)(l * 2) * cD,
                                     dec_ln2 + (long)(l * 2 + 1) * cD, xn_bf);
        gemm_bf16_k<2, 2><<<gDD, 256, 0, stream>>>(
            xn_bf, dec_cwq_t + (long)l * DD, nullptr, nullptr, qb, nullptr,
            cD, cD, 0, 0, 0, 0);
        gemm_bf16_k<2, 2><<<dim3(cD / 64, cN / 64, 2), 256, 0, stream>>>(
            enc_bf, dec_cwkv_t + (long)l * 2 * DD, nullptr, nullptr, kb, nullptr,
            cD, cD, 0, DD, ND, 0);
        attn_k<<<gAttn, 128, 0, stream>>>(qb, kb, vb, ob_bf, 0);
        gemm_bf16_k<2, 2><<<gDD, 256, 0, stream>>>(
            ob_bf, dec_cwo_t + (long)l * DD, nullptr, x_d, x_d, nullptr,
            cD, cD, 0, 0, 0, 0);

        ln_k<<<cN, 256, 0, stream>>>(x_d, dec_ln3 + (long)(l * 2) * cD,
                                     dec_ln3 + (long)(l * 2 + 1) * cD, xn_bf);
        gemm_bf16_k<2, 2><<<gF1, 256, 0, stream>>>(
            xn_bf, dec_w1_t + (long)l * DF, dec_b1 + (long)l * cF, nullptr,
            nullptr, hb_bf, cF, cD, 1, 0, 0, 0);
        gemm_bf16_k<2, 2><<<gDD, 256, 0, stream>>>(
            hb_bf, dec_w2_t + (long)l * DF, dec_b2 + (long)l * cD, x_d, x_d,
            nullptr, cD, cF, 0, 0, 0, 0);
    }
    ln_k<<<cN, 256, 0, stream>>>(x_d, dec_lnf, dec_lnf + cD, xn_bf);

    // ---- generator (bf16 MFMA, XCD swizzle) + log_softmax ----
    gemm_bf16_k<4, 2><<<dim3(cV / 64, cN / 128), 256, 0, stream>>>(
        xn_bf, gen_t, gen_b, nullptr, (float*)d_out, nullptr,
        cV, cD, 0, 0, 0, 1);
    lsm_k<<<cN, 256, 0, stream>>>((float*)d_out);
}

// Round 4
// 531.424 us; speedup vs baseline: 2.8202x; 1.1252x over previous
//
#include <hip/hip_runtime.h>
#include <cstddef>

// Problem constants (from reference)
constexpr int cB = 4, cS = 128, cD = 512, cH = 8, cDK = 64, cF = 2048, cL = 2, cV = 32000;
constexpr int cN = cB * cS; // 512

typedef __attribute__((ext_vector_type(8))) short short8;   // 8 x bf16 (MFMA frag)
typedef __attribute__((ext_vector_type(4))) float f32x4;    // MFMA acc / float4

__device__ __forceinline__ short f2bf(float x) {            // RNE fp32->bf16
    unsigned u = __builtin_bit_cast(unsigned, x);
    unsigned r = (u + 0x7fffu + ((u >> 16) & 1u)) >> 16;
    return (short)r;
}

// ---------------------------------------------------------------------------
// Embedding + positional encoding (fp32 residual stream)
// ---------------------------------------------------------------------------
__global__ __launch_bounds__(256) void embed_k(const float* __restrict__ emb,
                                               const int* __restrict__ tok,
                                               float* __restrict__ X)
{
    int n = blockIdx.x;
    int tid = threadIdx.x;
    int t = tok[n];
    int pos = n & (cS - 1);
    const float scale = 22.62741699796952f; // sqrt(512)
    for (int d = tid; d < cD; d += 256) {
        int i2 = d & ~1;
        float div = expf(-9.210340371976184f * (float)i2 / (float)cD);
        float arg = (float)pos * div;
        float p = (d & 1) ? cosf(arg) : sinf(arg);
        X[(long)n * cD + d] = emb[(long)t * cD + d] * scale + p;
    }
}

// ---------------------------------------------------------------------------
// LayerNorm -> bf16 (only used once, before the generator GEMM)
// ---------------------------------------------------------------------------
__global__ __launch_bounds__(256) void ln_k(const float* __restrict__ X,
                                            const float* __restrict__ g,
                                            const float* __restrict__ bta,
                                            short* __restrict__ Yb)
{
    __shared__ float red[256];
    int row = blockIdx.x, tid = threadIdx.x;
    const float* x = X + (long)row * cD;
    float v0 = x[tid], v1 = x[tid + 256];

    red[tid] = v0 + v1;
    __syncthreads();
    for (int st = 128; st > 0; st >>= 1) { if (tid < st) red[tid] += red[tid + st]; __syncthreads(); }
    float mu = red[0] * (1.0f / (float)cD);
    __syncthreads();

    float d0 = v0 - mu, d1 = v1 - mu;
    red[tid] = d0 * d0 + d1 * d1;
    __syncthreads();
    for (int st = 128; st > 0; st >>= 1) { if (tid < st) red[tid] += red[tid + st]; __syncthreads(); }
    float var = red[0] * (1.0f / (float)cD);
    float rs = rsqrtf(var + 1e-5f);

    Yb[(long)row * cD + tid]       = f2bf(g[tid]       * d0 * rs + bta[tid]);
    Yb[(long)row * cD + tid + 256] = f2bf(g[tid + 256] * d1 * rs + bta[tid + 256]);
}

// ---------------------------------------------------------------------------
// Batched transpose-convert: z slices fp32 [K][N] -> bf16 [N][K] contiguous.
// 64x64 tile, float4 loads, short8 stores. Pointers passed by-value struct.
// ---------------------------------------------------------------------------
struct TCP { const float* s[24]; };

__global__ __launch_bounds__(256) void tconv_k(TCP ptrs, short* __restrict__ dst,
                                               int K, int N)
{
    __shared__ float t[64][65];
    const float* s = ptrs.s[blockIdx.z];
    short* d = dst + (long)blockIdx.z * K * N;
    int k0 = blockIdx.y * 64, n0 = blockIdx.x * 64;
    int tid = threadIdx.x;
    const f32x4* s4 = (const f32x4*)s;
#pragma unroll
    for (int i = 0; i < 4; i++) {
        int lin = tid + i * 256;          // 1024 float4 chunks = 64 rows x 16
        int r = lin >> 4, c4 = lin & 15;
        f32x4 v = s4[(long)(k0 + r) * (N >> 2) + (n0 >> 2) + c4];
        t[r][c4 * 4 + 0] = v[0]; t[r][c4 * 4 + 1] = v[1];
        t[r][c4 * 4 + 2] = v[2]; t[r][c4 * 4 + 3] = v[3];
    }
    __syncthreads();
#pragma unroll
    for (int i = 0; i < 2; i++) {
        int lin = tid + i * 256;          // 512 short8 chunks = 64 n-rows x 8
        int r = lin >> 3, c8 = lin & 7;
        short8 o;
#pragma unroll
        for (int j = 0; j < 8; j++) o[j] = f2bf(t[c8 * 8 + j][r]);
        *(short8*)&d[(long)(n0 + r) * K + k0 + c8 * 8] = o;
    }
}

// ---------------------------------------------------------------------------
// bf16 MFMA GEMM, double-buffered LDS, BK=64, one barrier per K-step.
//   C = act(LN?(A) @ B + bias) + res
// LNF: A is fp32; per-block LN stats (mu, rsqrt var) are computed in a
// prologue over the block's rows (L2-hot), normalization fused into A-stage.
// A (bf16 path) row-major [M][K]; Bt bf16 transposed [N][K].
// 256 threads = 4 waves (2x2); block tile (MR*32) x (NR*32).
// LDS pitch 72 shorts -> frag ds_read_b128 is 2-way max (free, m136).
// ---------------------------------------------------------------------------
template <int MR, int NR, bool LNF>
__global__ __launch_bounds__(256) void gemm_k(
    const short* __restrict__ Abf, const float* __restrict__ Af,
    const float* __restrict__ lng, const float* __restrict__ lnb,
    const short* __restrict__ Bt,
    const float* __restrict__ bias, const float* __restrict__ res,
    float* __restrict__ C, short* __restrict__ Cb,
    int N, int K, int relu, long btStride, long cStride, int swz)
{
    constexpr int BM = MR * 32, BN = NR * 32, BK = 64, PITCH = BK + 8;
    constexpr int ACH = (BM * BK) / (8 * 256);   // short8 chunks / thread
    constexpr int BCH = (BN * BK) / (8 * 256);
    static_assert(ACH >= 1 && BCH >= 1, "tile too small");
    __shared__ short As[2][BM * PITCH];
    __shared__ short Bs[2][BN * PITCH];
    __shared__ float mu_s[BM], rs_s[BM];

    int bx = blockIdx.x, by = blockIdx.y;
    if (swz) {  // XCD grouping (nb % 8 == 0 for all call sites using swz)
        int nb = gridDim.x * gridDim.y;
        int bid = by * gridDim.x + bx;
        int w = (bid & 7) * (nb >> 3) + (bid >> 3);
        by = w % gridDim.y; bx = w / gridDim.y;
    }

    const short* Bm = Bt + (long)blockIdx.z * btStride;
    int tid = threadIdx.x;
    int lane = tid & 63, wid = tid >> 6;
    int wr = wid >> 1, wc = wid & 1;
    int m0 = by * BM, n0 = bx * BN;
    int lrow = lane & 15, koff = (lane >> 4) * 8;

    if constexpr (LNF) {   // per-row LN stats over K (=512 at all LNF sites)
        constexpr int TPR = 256 / BM;            // threads per row
        int r = tid / TPR, sub = tid % TPR;
        const f32x4* row4 = (const f32x4*)(Af + (long)(m0 + r) * K);
        float s = 0.f, s2 = 0.f;
        for (int i = sub; i < (K >> 2); i += TPR) {
            f32x4 v = row4[i];
            s  += v[0] + v[1] + v[2] + v[3];
            s2 += v[0] * v[0] + v[1] * v[1] + v[2] * v[2] + v[3] * v[3];
        }
#pragma unroll
        for (int o = TPR >> 1; o > 0; o >>= 1) {
            s += __shfl_xor(s, o); s2 += __shfl_xor(s2, o);
        }
        if (sub == 0) {
            float mu = s / (float)K;
            float var = s2 / (float)K - mu * mu;
            mu_s[r] = mu; rs_s[r] = rsqrtf(var + 1e-5f);
        }
        __syncthreads();
    }

    f32x4 acc[MR][NR];
#pragma unroll
    for (int m = 0; m < MR; m++)
#pragma unroll
        for (int n = 0; n < NR; n++) acc[m][n] = f32x4{0.f, 0.f, 0.f, 0.f};

    short8 ra[ACH], rb[BCH];
    auto stage = [&](int k0) {
#pragma unroll
        for (int i = 0; i < ACH; i++) {
            int lin = tid + i * 256;
            int r = lin >> 3, c8 = lin & 7;      // 8 chunks per row (BK=64)
            if constexpr (LNF) {
                const f32x4* p = (const f32x4*)(Af + (long)(m0 + r) * K + k0 + c8 * 8);
                f32x4 f0 = p[0], f1 = p[1];
                f32x4 g0 = *(const f32x4*)&lng[k0 + c8 * 8];
                f32x4 g1 = *(const f32x4*)&lng[k0 + c8 * 8 + 4];
                f32x4 b0 = *(const f32x4*)&lnb[k0 + c8 * 8];
                f32x4 b1 = *(const f32x4*)&lnb[k0 + c8 * 8 + 4];
                float mu = mu_s[r], rs = rs_s[r];
                short8 o;
#pragma unroll
                for (int j = 0; j < 4; j++) o[j]     = f2bf((f0[j] - mu) * rs * g0[j] + b0[j]);
#pragma unroll
                for (int j = 0; j < 4; j++) o[4 + j] = f2bf((f1[j] - mu) * rs * g1[j] + b1[j]);
                ra[i] = o;
            } else {
                ra[i] = *(const short8*)&Abf[(long)(m0 + r) * K + k0 + c8 * 8];
            }
        }
#pragma unroll
        for (int i = 0; i < BCH; i++) {
            int lin = tid + i * 256;
            int r = lin >> 3, c8 = lin & 7;
            rb[i] = *(const short8*)&Bm[(long)(n0 + r) * K + k0 + c8 * 8];
        }
    };

    stage(0);
    int cur = 0;
    for (int k0 = 0; k0 < K; k0 += BK) {
        // write staged tile (k0) into buf cur
#pragma unroll
        for (int i = 0; i < ACH; i++) {
            int lin = tid + i * 256, r = lin >> 3, c8 = lin & 7;
            *(short8*)&As[cur][r * PITCH + c8 * 8] = ra[i];
        }
#pragma unroll
        for (int i = 0; i < BCH; i++) {
            int lin = tid + i * 256, r = lin >> 3, c8 = lin & 7;
            *(short8*)&Bs[cur][r * PITCH + c8 * 8] = rb[i];
        }
        __syncthreads();                       // single barrier per K-step
        if (k0 + BK < K) stage(k0 + BK);       // prefetch overlaps MFMAs

#pragma unroll
        for (int kk = 0; kk < BK; kk += 32) {
            short8 a[MR], b[NR];
#pragma unroll
            for (int m = 0; m < MR; m++)
                a[m] = *(const short8*)&As[cur][(wr * MR * 16 + m * 16 + lrow) * PITCH + kk + koff];
#pragma unroll
            for (int n = 0; n < NR; n++)
                b[n] = *(const short8*)&Bs[cur][(wc * NR * 16 + n * 16 + lrow) * PITCH + kk + koff];
#pragma unroll
            for (int m = 0; m < MR; m++)
#pragma unroll
                for (int n = 0; n < NR; n++)
                    acc[m][n] = __builtin_amdgcn_mfma_f32_16x16x32_bf16(a[m], b[n], acc[m][n], 0, 0, 0);
        }
        cur ^= 1;
    }

    // epilogue: C/D layout col=lane&15, row=(lane>>4)*4+j  [m89]
#pragma unroll
    for (int m = 0; m < MR; m++) {
        int rbase = m0 + wr * MR * 16 + m * 16 + (lane >> 4) * 4;
#pragma unroll
        for (int n = 0; n < NR; n++) {
            int col = n0 + wc * NR * 16 + n * 16 + (lane & 15);
            float bv = bias ? bias[col] : 0.f;
#pragma unroll
            for (int j = 0; j < 4; j++) {
                long row = rbase + j;
                float v = acc[m][n][j] + bv;
                if (res)  v += res[row * N + col];
                if (relu) v = fmaxf(v, 0.f);
                long off = row * N + col + (long)blockIdx.z * cStride;
                if (C)  C[off] = v;
                if (Cb) Cb[off] = f2bf(v);
            }
        }
    }
}

// ---------------------------------------------------------------------------
// Attention, one block per (dst pos, head, batch). Exact reference formula:
// s = exp(clip(q.k/8, +-10)); o = sum(s*v)/sum(s); causal masks src>dst.
// ---------------------------------------------------------------------------
__global__ __launch_bounds__(128) void attn_k(const float* __restrict__ Q,
                                              const float* __restrict__ Km,
                                              const float* __restrict__ Vm,
                                              short* __restrict__ O, int causal)
{
    __shared__ float ks[cDK][cS + 1];
    __shared__ float qs[cDK];
    __shared__ float ss[cS];
    __shared__ float red[cS];
    __shared__ float pv[2][cDK];

    int tid = threadIdx.x;
    int dst = blockIdx.x;
    int h = blockIdx.y, b = blockIdx.z;
    long base = ((long)b * cS) * (cH * cDK) + h * cDK;

    if (tid < cDK) qs[tid] = Q[((long)(b * cS + dst)) * (cH * cDK) + h * cDK + tid];
    for (int i = 0; i < (cS * cDK) / 128; i++) {
        int lin = tid + i * 128;
        int src = lin >> 6, d = lin & 63;
        ks[d][src] = Km[base + (long)src * (cH * cDK) + d];
    }
    __syncthreads();

    float dot = 0.0f;
#pragma unroll
    for (int d = 0; d < cDK; d++) dot += ks[d][tid] * qs[d];
    dot *= 0.125f;
    dot = fminf(fmaxf(dot, -10.0f), 10.0f);
    float s = expf(dot);
    if (causal && tid > dst) s = 0.0f;
    ss[tid] = s;
    red[tid] = s;
    __syncthreads();
    for (int st = 64; st > 0; st >>= 1) { if (tid < st) red[tid] += red[tid + st]; __syncthreads(); }
    float z = red[0];

    int half = tid >> 6, d = tid & 63;
    float acc = 0.0f;
    for (int src = half * 64; src < half * 64 + 64; src++)
        acc += ss[src] * Vm[base + (long)src * (cH * cDK) + d];
    pv[half][d] = acc;
    __syncthreads();

    if (tid < cDK)
        O[((long)(b * cS + dst)) * (cH * cDK) + h * cDK + tid] = f2bf((pv[0][tid] + pv[1][tid]) / z);
}

// ---------------------------------------------------------------------------
// In-place row log_softmax over V=32000: online max+sum (1 read) + write pass
// ---------------------------------------------------------------------------
__global__ __launch_bounds__(256) void lsm_k(float* __restrict__ X)
{
    __shared__ float rm[256], rs[256];
    int row = blockIdx.x, tid = threadIdx.x;
    f32x4* x4 = (f32x4*)(X + (long)row * cV);
    constexpr int NV = cV / 4;

    float m = -1e30f, s = 0.f;
    for (int i = tid; i < NV; i += 256) {
        f32x4 v = x4[i];
        float cm = fmaxf(fmaxf(v[0], v[1]), fmaxf(v[2], v[3]));
        float nm = fmaxf(m, cm);
        s = s * __expf(m - nm)
          + __expf(v[0] - nm) + __expf(v[1] - nm)
          + __expf(v[2] - nm) + __expf(v[3] - nm);
        m = nm;
    }
    rm[tid] = m; rs[tid] = s;
    __syncthreads();
    for (int st = 128; st > 0; st >>= 1) {
        if (tid < st) {
            float m2 = rm[tid + st], s2 = rs[tid + st];
            float nm = fmaxf(rm[tid], m2);
            rs[tid] = rs[tid] * __expf(rm[tid] - nm) + s2 * __expf(m2 - nm);
            rm[tid] = nm;
        }
        __syncthreads();
    }
    float lse = rm[0] + __logf(rs[0]);

    for (int i = tid; i < NV; i += 256) {
        f32x4 v = x4[i];
        v[0] -= lse; v[1] -= lse; v[2] -= lse; v[3] -= lse;
        x4[i] = v;
    }
}

// ---------------------------------------------------------------------------
extern "C" void kernel_launch(void* const* d_in, const int* in_sizes, int n_in,
                              void* d_out, int out_size, void* d_ws, size_t ws_size,
                              hipStream_t stream)
{
    const float* src_emb  = (const float*)d_in[0];
    const float* tgt_emb  = (const float*)d_in[1];
    const float* enc_Wqkv = (const float*)d_in[2];
    const float* enc_Wo   = (const float*)d_in[3];
    const float* enc_ln1  = (const float*)d_in[4];
    const float* enc_W1   = (const float*)d_in[5];
    const float* enc_b1   = (const float*)d_in[6];
    const float* enc_W2   = (const float*)d_in[7];
    const float* enc_b2   = (const float*)d_in[8];
    const float* enc_ln2  = (const float*)d_in[9];
    const float* enc_lnf  = (const float*)d_in[10];
    const float* dec_Wqkv = (const float*)d_in[11];
    const float* dec_Wo   = (const float*)d_in[12];
    const float* dec_ln1  = (const float*)d_in[13];
    const float* dec_cWq  = (const float*)d_in[14];
    const float* dec_cWkv = (const float*)d_in[15];
    const float* dec_cWo  = (const float*)d_in[16];
    const float* dec_ln2  = (const float*)d_in[17];
    const float* dec_W1   = (const float*)d_in[18];
    const float* dec_b1   = (const float*)d_in[19];
    const float* dec_W2   = (const float*)d_in[20];
    const float* dec_b2   = (const float*)d_in[21];
    const float* dec_ln3  = (const float*)d_in[22];
    const float* dec_lnf  = (const float*)d_in[23];
    const float* gen_W    = (const float*)d_in[24];
    const float* gen_b    = (const float*)d_in[25];
    const int* src_tok    = (const int*)d_in[26];
    const int* tgt_tok    = (const int*)d_in[27];
    // edge lists (28..33): fixed structure (full / causal) -> unused

    const long ND = (long)cN * cD;          // 262144
    const long DD = (long)cD * cD;          // 262144
    const long DF = (long)cD * cF;          // 1048576

    // fp32 region
    float* x_e = (float*)d_ws;
    float* x_d = x_e + ND;
    float* qb  = x_d + ND;
    float* kb  = qb + ND;   // q,k,v contiguous (z-batched GEMM output)
    float* vb  = kb + ND;
    float* kvc = vb + ND;   // cross K/V for both layers: [4][N,D]

    // bf16 region
    short* xn_bf = (short*)(kvc + 4 * ND);  // [N,D] (generator LN output)
    short* ob_bf = xn_bf + ND;              // [N,D]
    short* hb_bf = ob_bf + ND;              // [N,F]
    // transposed bf16 weights
    short* wDD  = hb_bf + (long)cN * cF;    // 24 x [D][D]
    short* wDF  = wDD + 24 * DD;            // 4  x [F][D]  (W1 slices)
    short* wFD  = wDF + 4 * DF;             // 4  x [D][F]  (W2 slices)
    short* genT = wFD + 4 * DF;             // [V][D]

    // DD slice order (dst = wDD + idx*DD):
    //  0-5 enc_Wqkv (l0 q,k,v; l1 q,k,v) | 6-7 enc_Wo | 8-13 dec_Wqkv
    //  14-15 dec_Wo | 16-17 dec_cWq | 18-21 dec_cWkv (l0k,l0v,l1k,l1v) | 22-23 dec_cWo
    {
        TCP p{};
        int i = 0;
        for (int j = 0; j < 6; j++) p.s[i++] = enc_Wqkv + (long)j * DD;
        for (int j = 0; j < 2; j++) p.s[i++] = enc_Wo   + (long)j * DD;
        for (int j = 0; j < 6; j++) p.s[i++] = dec_Wqkv + (long)j * DD;
        for (int j = 0; j < 2; j++) p.s[i++] = dec_Wo   + (long)j * DD;
        for (int j = 0; j < 2; j++) p.s[i++] = dec_cWq  + (long)j * DD;
        for (int j = 0; j < 4; j++) p.s[i++] = dec_cWkv + (long)j * DD;
        for (int j = 0; j < 2; j++) p.s[i++] = dec_cWo  + (long)j * DD;
        tconv_k<<<dim3(cD / 64, cD / 64, 24), 256, 0, stream>>>(p, wDD, cD, cD);
    }
    {
        TCP p{};
        p.s[0] = enc_W1; p.s[1] = enc_W1 + DF; p.s[2] = dec_W1; p.s[3] = dec_W1 + DF;
        tconv_k<<<dim3(cF / 64, cD / 64, 4), 256, 0, stream>>>(p, wDF, cD, cF);
    }
    {
        TCP p{};
        p.s[0] = enc_W2; p.s[1] = enc_W2 + DF; p.s[2] = dec_W2; p.s[3] = dec_W2 + DF;
        tconv_k<<<dim3(cD / 64, cF / 64, 4), 256, 0, stream>>>(p, wFD, cF, cD);
    }
    {
        TCP p{};
        p.s[0] = gen_W;
        tconv_k<<<dim3(cV / 64, cD / 64, 1), 256, 0, stream>>>(p, genT, cD, cV);
    }

    embed_k<<<cN, 256, 0, stream>>>(src_emb, src_tok, x_e);
    embed_k<<<cN, 256, 0, stream>>>(tgt_emb, tgt_tok, x_d);

    dim3 gDD11(cD / 32, cN / 32);            // <1,1>: 256 blocks
    dim3 gFFN1(cF / 64, cN / 64);            // <2,2>: 256 blocks
    dim3 gAttn(cS, cH, cB);

    // ---- encoder ----
    for (int l = 0; l < cL; l++) {
        // LN1 + QKV (z=3)
        gemm_k<1, 1, true><<<dim3(cD / 32, cN / 32, 3), 256, 0, stream>>>(
            nullptr, x_e, enc_ln1 + (long)(2 * l) * cD, enc_ln1 + (long)(2 * l + 1) * cD,
            wDD + (long)(3 * l) * DD, nullptr, nullptr, qb, nullptr,
            cD, cD, 0, DD, ND, 0);
        attn_k<<<gAttn, 128, 0, stream>>>(qb, kb, vb, ob_bf, 0);
        gemm_k<1, 1, false><<<gDD11, 256, 0, stream>>>(
            ob_bf, nullptr, nullptr, nullptr, wDD + (long)(6 + l) * DD,
            nullptr, x_e, x_e, nullptr, cD, cD, 0, 0, 0, 0);
        // LN2 + FFN1 (relu)
        gemm_k<2, 2, true><<<gFFN1, 256, 0, stream>>>(
            nullptr, x_e, enc_ln2 + (long)(2 * l) * cD, enc_ln2 + (long)(2 * l + 1) * cD,
            wDF + (long)l * DF, enc_b1 + (long)l * cF, nullptr, nullptr, hb_bf,
            cF, cD, 1, 0, 0, 0);
        gemm_k<1, 1, false><<<gDD11, 256, 0, stream>>>(
            hb_bf, nullptr, nullptr, nullptr, wFD + (long)l * DF,
            enc_b2 + (long)l * cD, x_e, x_e, nullptr, cD, cF, 0, 0, 0, 0);
    }

    // ---- cross K/V for both decoder layers (enc_lnf fused), z=4 ----
    gemm_k<1, 1, true><<<dim3(cD / 32, cN / 32, 4), 256, 0, stream>>>(
        nullptr, x_e, enc_lnf, enc_lnf + cD,
        wDD + 18 * DD, nullptr, nullptr, kvc, nullptr,
        cD, cD, 0, DD, ND, 0);

    // ---- decoder ----
    for (int l = 0; l < cL; l++) {
        // LN1 + self QKV (z=3)
        gemm_k<1, 1, true><<<dim3(cD / 32, cN / 32, 3), 256, 0, stream>>>(
            nullptr, x_d, dec_ln1 + (long)(2 * l) * cD, dec_ln1 + (long)(2 * l + 1) * cD,
            wDD + (long)(8 + 3 * l) * DD, nullptr, nullptr, qb, nullptr,
            cD, cD, 0, DD, ND, 0);
        attn_k<<<gAttn, 128, 0, stream>>>(qb, kb, vb, ob_bf, 1);
        gemm_k<1, 1, false><<<gDD11, 256, 0, stream>>>(
            ob_bf, nullptr, nullptr, nullptr, wDD + (long)(14 + l) * DD,
            nullptr, x_d, x_d, nullptr, cD, cD, 0, 0, 0, 0);
        // LN2 + cross Q
        gemm_k<1, 1, true><<<gDD11, 256, 0, stream>>>(
            nullptr, x_d, dec_ln2 + (long)(2 * l) * cD, dec_ln2 + (long)(2 * l + 1) * cD,
            wDD + (long)(16 + l) * DD, nullptr, nullptr, qb, nullptr,
            cD, cD, 0, 0, 0, 0);
        attn_k<<<gAttn, 128, 0, stream>>>(qb, kvc + (long)(2 * l) * ND,
                                          kvc + (long)(2 * l + 1) * ND, ob_bf, 0);
        gemm_k<1, 1, false><<<gDD11, 256, 0, stream>>>(
            ob_bf, nullptr, nullptr, nullptr, wDD + (long)(22 + l) * DD,
            nullptr, x_d, x_d, nullptr, cD, cD, 0, 0, 0, 0);
        // LN3 + FFN1 (relu)
        gemm_k<2, 2, true><<<gFFN1, 256, 0, stream>>>(
            nullptr, x_d, dec_ln3 + (long)(2 * l) * cD, dec_ln3 + (long)(2 * l + 1) * cD,
            wDF + (long)(2 + l) * DF, dec_b1 + (long)l * cF, nullptr, nullptr, hb_bf,
            cF, cD, 1, 0, 0, 0);
        gemm_k<1, 1, false><<<gDD11, 256, 0, stream>>>(
            hb_bf, nullptr, nullptr, nullptr, wFD + (long)(2 + l) * DF,
            dec_b2 + (long)l * cD, x_d, x_d, nullptr, cD, cF, 0, 0, 0, 0);
    }

    // ---- final LN + generator + log_softmax ----
    ln_k<<<cN, 256, 0, stream>>>(x_d, dec_lnf, dec_lnf + cD, xn_bf);
    gemm_k<4, 2, false><<<dim3(cV / 64, cN / 128), 256, 0, stream>>>(
        xn_bf, nullptr, nullptr, nullptr, genT, gen_b, nullptr,
        (float*)d_out, nullptr, cV, cD, 0, 0, 0, 1);
    lsm_k<<<cN, 256, 0, stream>>>((float*)d_out);
}

// Round 5
// 377.798 us; speedup vs baseline: 3.9669x; 1.4066x over previous
//
#include <hip/hip_runtime.h>
#include <cstddef>

// Problem constants (from reference)
constexpr int cB = 4, cS = 128, cD = 512, cH = 8, cDK = 64, cF = 2048, cL = 2, cV = 32000;
constexpr int cN = cB * cS; // 512

typedef __attribute__((ext_vector_type(8))) short short8;   // 8 x bf16 (MFMA frag)
typedef __attribute__((ext_vector_type(4))) float f32x4;    // MFMA acc / float4

__device__ __forceinline__ short f2bf(float x) {            // RNE fp32->bf16
    unsigned u = __builtin_bit_cast(unsigned, x);
    unsigned r = (u + 0x7fffu + ((u >> 16) & 1u)) >> 16;
    return (short)r;
}

// ---------------------------------------------------------------------------
// Embedding + positional encoding (fp32 residual stream)
// ---------------------------------------------------------------------------
__global__ __launch_bounds__(256) void embed_k(const float* __restrict__ emb,
                                               const int* __restrict__ tok,
                                               float* __restrict__ X)
{
    int n = blockIdx.x;
    int tid = threadIdx.x;
    int t = tok[n];
    int pos = n & (cS - 1);
    const float scale = 22.62741699796952f; // sqrt(512)
    for (int d = tid; d < cD; d += 256) {
        int i2 = d & ~1;
        float div = expf(-9.210340371976184f * (float)i2 / (float)cD);
        float arg = (float)pos * div;
        float p = (d & 1) ? cosf(arg) : sinf(arg);
        X[(long)n * cD + d] = emb[(long)t * cD + d] * scale + p;
    }
}

// ---------------------------------------------------------------------------
// LayerNorm -> bf16 (used once, before the generator GEMM)
// ---------------------------------------------------------------------------
__global__ __launch_bounds__(256) void ln_k(const float* __restrict__ X,
                                            const float* __restrict__ g,
                                            const float* __restrict__ bta,
                                            short* __restrict__ Yb)
{
    __shared__ float red[256];
    int row = blockIdx.x, tid = threadIdx.x;
    const float* x = X + (long)row * cD;
    float v0 = x[tid], v1 = x[tid + 256];

    red[tid] = v0 + v1;
    __syncthreads();
    for (int st = 128; st > 0; st >>= 1) { if (tid < st) red[tid] += red[tid + st]; __syncthreads(); }
    float mu = red[0] * (1.0f / (float)cD);
    __syncthreads();

    float d0 = v0 - mu, d1 = v1 - mu;
    red[tid] = d0 * d0 + d1 * d1;
    __syncthreads();
    for (int st = 128; st > 0; st >>= 1) { if (tid < st) red[tid] += red[tid + st]; __syncthreads(); }
    float var = red[0] * (1.0f / (float)cD);
    float rs = rsqrtf(var + 1e-5f);

    Yb[(long)row * cD + tid]       = f2bf(g[tid]       * d0 * rs + bta[tid]);
    Yb[(long)row * cD + tid + 256] = f2bf(g[tid + 256] * d1 * rs + bta[tid + 256]);
}

// ---------------------------------------------------------------------------
// Batched transpose-convert: z slices fp32 [K][N] -> bf16 [N][K] contiguous.
// ---------------------------------------------------------------------------
struct TCP { const float* s[24]; };

__global__ __launch_bounds__(256) void tconv_k(TCP ptrs, short* __restrict__ dst,
                                               int K, int N)
{
    __shared__ float t[64][65];
    const float* s = ptrs.s[blockIdx.z];
    short* d = dst + (long)blockIdx.z * K * N;
    int k0 = blockIdx.y * 64, n0 = blockIdx.x * 64;
    int tid = threadIdx.x;
    const f32x4* s4 = (const f32x4*)s;
#pragma unroll
    for (int i = 0; i < 4; i++) {
        int lin = tid + i * 256;
        int r = lin >> 4, c4 = lin & 15;
        f32x4 v = s4[(long)(k0 + r) * (N >> 2) + (n0 >> 2) + c4];
        t[r][c4 * 4 + 0] = v[0]; t[r][c4 * 4 + 1] = v[1];
        t[r][c4 * 4 + 2] = v[2]; t[r][c4 * 4 + 3] = v[3];
    }
    __syncthreads();
#pragma unroll
    for (int i = 0; i < 2; i++) {
        int lin = tid + i * 256;
        int r = lin >> 3, c8 = lin & 7;
        short8 o;
#pragma unroll
        for (int j = 0; j < 8; j++) o[j] = f2bf(t[c8 * 8 + j][r]);
        *(short8*)&d[(long)(n0 + r) * K + k0 + c8 * 8] = o;
    }
}

// ---------------------------------------------------------------------------
// bf16 MFMA GEMM, double-buffered LDS + DEPTH-2 register prefetch queue.
//   C = act(LN?(A) @ B + bias) + res
// A (bf16) row-major [M][K] or fp32 with fused LN; Bt bf16 transposed [N][K].
// 256 threads = 4 waves (2x2); block tile (MR*32) x (NR*32); BK=64.
// Named queue slots (no runtime indexing -> stays in VGPRs, rule #20).
// ---------------------------------------------------------------------------
template <int MR, int NR, bool LNF>
__global__ __launch_bounds__(256) void gemm_k(
    const short* __restrict__ Abf, const float* __restrict__ Af,
    const float* __restrict__ lng, const float* __restrict__ lnb,
    const short* __restrict__ Bt,
    const float* __restrict__ bias, const float* __restrict__ res,
    float* __restrict__ C, short* __restrict__ Cb,
    int N, int K, int relu, long btStride, long cStride, int swz)
{
    constexpr int BM = MR * 32, BN = NR * 32, BK = 64, PITCH = BK + 8;
    constexpr int ACH = (BM * BK) / (8 * 256);   // short8 chunks / thread
    constexpr int BCH = (BN * BK) / (8 * 256);
    static_assert(ACH >= 1 && BCH >= 1, "tile too small");
    __shared__ short As[2][BM * PITCH];
    __shared__ short Bs[2][BN * PITCH];
    __shared__ float mu_s[BM], rs_s[BM];
    __shared__ float gb_s[2][512];               // LN gamma/beta (LNF: K==512)

    int bx = blockIdx.x, by = blockIdx.y;
    if (swz) {  // XCD grouping (grid count % 8 == 0 at swz call sites)
        int nb = gridDim.x * gridDim.y;
        int bid = by * gridDim.x + bx;
        int w = (bid & 7) * (nb >> 3) + (bid >> 3);
        by = w % gridDim.y; bx = w / gridDim.y;
    }

    const short* Bm = Bt + (long)blockIdx.z * btStride;
    int tid = threadIdx.x;
    int lane = tid & 63, wid = tid >> 6;
    int wr = wid >> 1, wc = wid & 1;
    int m0 = by * BM, n0 = bx * BN;
    int lrow = lane & 15, koff = (lane >> 4) * 8;

    f32x4 acc[MR][NR];
#pragma unroll
    for (int m = 0; m < MR; m++)
#pragma unroll
        for (int n = 0; n < NR; n++) acc[m][n] = f32x4{0.f, 0.f, 0.f, 0.f};

    // register queues (two named slots each)
    short8 qa0[ACH], qa1[ACH], qb0[BCH], qb1[BCH];
    f32x4 fa0[LNF ? ACH * 2 : 1], fa1[LNF ? ACH * 2 : 1];

    auto stageA = [&](int k0, short8 (&qa)[ACH], f32x4 (&fa)[LNF ? ACH * 2 : 1]) {
#pragma unroll
        for (int i = 0; i < ACH; i++) {
            int lin = tid + i * 256, r = lin >> 3, c8 = lin & 7;
            if constexpr (LNF) {
                const f32x4* p = (const f32x4*)(Af + (long)(m0 + r) * K + k0 + c8 * 8);
                fa[2 * i] = p[0]; fa[2 * i + 1] = p[1];
            } else {
                qa[i] = *(const short8*)&Abf[(long)(m0 + r) * K + k0 + c8 * 8];
            }
        }
    };
    auto stageB = [&](int k0, short8 (&qb)[BCH]) {
#pragma unroll
        for (int i = 0; i < BCH; i++) {
            int lin = tid + i * 256, r = lin >> 3, c8 = lin & 7;
            qb[i] = *(const short8*)&Bm[(long)(n0 + r) * K + k0 + c8 * 8];
        }
    };
    auto writeT = [&](int buf, int k0, short8 (&qa)[ACH],
                      f32x4 (&fa)[LNF ? ACH * 2 : 1], short8 (&qb)[BCH]) {
#pragma unroll
        for (int i = 0; i < ACH; i++) {
            int lin = tid + i * 256, r = lin >> 3, c8 = lin & 7;
            if constexpr (LNF) {
                float mu = mu_s[r], rs = rs_s[r];
                short8 o;
#pragma unroll
                for (int j = 0; j < 4; j++)
                    o[j] = f2bf((fa[2 * i][j] - mu) * rs * gb_s[0][k0 + c8 * 8 + j] + gb_s[1][k0 + c8 * 8 + j]);
#pragma unroll
                for (int j = 0; j < 4; j++)
                    o[4 + j] = f2bf((fa[2 * i + 1][j] - mu) * rs * gb_s[0][k0 + c8 * 8 + 4 + j] + gb_s[1][k0 + c8 * 8 + 4 + j]);
                *(short8*)&As[buf][r * PITCH + c8 * 8] = o;
            } else {
                *(short8*)&As[buf][r * PITCH + c8 * 8] = qa[i];
            }
        }
#pragma unroll
        for (int i = 0; i < BCH; i++) {
            int lin = tid + i * 256, r = lin >> 3, c8 = lin & 7;
            *(short8*)&Bs[buf][r * PITCH + c8 * 8] = qb[i];
        }
    };
    auto mfmaStep = [&](int buf) {
#pragma unroll
        for (int kk = 0; kk < BK; kk += 32) {
            short8 a[MR], b[NR];
#pragma unroll
            for (int m = 0; m < MR; m++)
                a[m] = *(const short8*)&As[buf][(wr * MR * 16 + m * 16 + lrow) * PITCH + kk + koff];
#pragma unroll
            for (int n = 0; n < NR; n++)
                b[n] = *(const short8*)&Bs[buf][(wc * NR * 16 + n * 16 + lrow) * PITCH + kk + koff];
#pragma unroll
            for (int m = 0; m < MR; m++)
#pragma unroll
                for (int n = 0; n < NR; n++)
                    acc[m][n] = __builtin_amdgcn_mfma_f32_16x16x32_bf16(a[m], b[n], acc[m][n], 0, 0, 0);
        }
    };

    // issue first two stages ASAP
    stageA(0, qa0, fa0); stageB(0, qb0);
    if (BK < K) { stageA(BK, qa1, fa1); stageB(BK, qb1); }

    if constexpr (LNF) {   // LN stats + gamma/beta staging (K==512 at LNF sites)
        constexpr int TPR = 256 / BM;
        int r = tid / TPR, sub = tid % TPR;
        const f32x4* row4 = (const f32x4*)(Af + (long)(m0 + r) * K);
        float s = 0.f, s2 = 0.f;
        for (int i = sub; i < (K >> 2); i += TPR) {
            f32x4 v = row4[i];
            s  += v[0] + v[1] + v[2] + v[3];
            s2 += v[0] * v[0] + v[1] * v[1] + v[2] * v[2] + v[3] * v[3];
        }
#pragma unroll
        for (int o = TPR >> 1; o > 0; o >>= 1) {
            s += __shfl_xor(s, o); s2 += __shfl_xor(s2, o);
        }
        if (sub == 0) {
            float mu = s / (float)K;
            float var = s2 / (float)K - mu * mu;
            mu_s[r] = mu; rs_s[r] = rsqrtf(var + 1e-5f);
        }
        for (int i = tid; i < 512; i += 256) {
            gb_s[0][i] = lng[i]; gb_s[1][i] = lnb[i];
        }
        __syncthreads();
    }

    int k0 = 0;
    for (;;) {
        writeT(0, k0, qa0, fa0, qb0);
        __syncthreads();
        if (k0 + 2 * BK < K) { stageA(k0 + 2 * BK, qa0, fa0); stageB(k0 + 2 * BK, qb0); }
        mfmaStep(0);
        k0 += BK; if (k0 >= K) break;

        writeT(1, k0, qa1, fa1, qb1);
        __syncthreads();
        if (k0 + 2 * BK < K) { stageA(k0 + 2 * BK, qa1, fa1); stageB(k0 + 2 * BK, qb1); }
        mfmaStep(1);
        k0 += BK; if (k0 >= K) break;
    }

    // epilogue: C/D layout col=lane&15, row=(lane>>4)*4+j  [m89]
#pragma unroll
    for (int m = 0; m < MR; m++) {
        int rbase = m0 + wr * MR * 16 + m * 16 + (lane >> 4) * 4;
#pragma unroll
        for (int n = 0; n < NR; n++) {
            int col = n0 + wc * NR * 16 + n * 16 + (lane & 15);
            float bv = bias ? bias[col] : 0.f;
#pragma unroll
            for (int j = 0; j < 4; j++) {
                long row = rbase + j;
                float v = acc[m][n][j] + bv;
                if (res)  v += res[row * N + col];
                if (relu) v = fmaxf(v, 0.f);
                long off = row * N + col + (long)blockIdx.z * cStride;
                if (C)  C[off] = v;
                if (Cb) Cb[off] = f2bf(v);
            }
        }
    }
}

// ---------------------------------------------------------------------------
// MFMA attention: block = (head, batch, dst-half of 64). 256 threads, 4 waves.
// q,k,v,o bf16 [token][H*DK]. Exact reference math:
//   s = exp(clip(q.k/8, +-10)); o = sum(s*v)/sum(s); causal masks src>dst.
// S = mfma(q_rows, k_rows) -> S[dst][src]; P bf16 to LDS;
// O^T = mfma(vt_rows, p_rows) -> O^T[dk][dst]; divide by z; scatter out.
// vt is [dk][src] with 16B-granule XOR swizzle (conflict-free scatter write).
// ---------------------------------------------------------------------------
__global__ __launch_bounds__(256) void attn_k(const short* __restrict__ Q,
                                              const short* __restrict__ Km,
                                              const short* __restrict__ Vm,
                                              short* __restrict__ O, int causal)
{
    __shared__ short q_s[64 * 72];     // [dst][dk]  pitch 72
    __shared__ short k_s[128 * 72];    // [src][dk]  pitch 72
    __shared__ short vt_s[64 * 128];   // [dk][src]  granule-swizzled, pitch 128
    __shared__ short p_s[64 * 136];    // [dst][src] pitch 136
    __shared__ float z_s[64];

    int tid = threadIdx.x, lane = tid & 63, wid = tid >> 6;
    int lr = lane & 15, lg = lane >> 4;
    int h = blockIdx.x, b = blockIdx.y, dstBase = blockIdx.z * 64;
    const int RS = cH * cDK; // 512
    long qbase = ((long)b * cS + dstBase) * RS + h * cDK;
    long kbase = ((long)b * cS) * RS + h * cDK;

    // stage q (64 rows) and k (128 rows), row-major [token][dk]
#pragma unroll
    for (int i = 0; i < 2; i++) {
        int lin = tid + i * 256, t = lin >> 3, c8 = lin & 7;
        *(short8*)&q_s[t * 72 + c8 * 8] = *(const short8*)&Q[qbase + (long)t * RS + c8 * 8];
    }
#pragma unroll
    for (int i = 0; i < 4; i++) {
        int lin = tid + i * 256, t = lin >> 3, c8 = lin & 7;
        *(short8*)&k_s[t * 72 + c8 * 8] = *(const short8*)&Km[kbase + (long)t * RS + c8 * 8];
    }
    // stage v transposed [dk][src] with granule-XOR swizzle
#pragma unroll
    for (int i = 0; i < 4; i++) {
        int lin = tid + i * 256, src = lin >> 3, c8 = lin & 7;
        short8 v = *(const short8*)&Vm[kbase + (long)src * RS + c8 * 8];
#pragma unroll
        for (int j = 0; j < 8; j++) {
            int dk = c8 * 8 + j;
            int g = (src >> 3) ^ (dk >> 3);
            vt_s[dk * 128 + g * 8 + (src & 7)] = v[j];
        }
    }
    __syncthreads();

    // ---- S = q @ k^T : wave computes 16 dst rows x 128 src ----
    f32x4 sacc[8];
#pragma unroll
    for (int n = 0; n < 8; n++) sacc[n] = f32x4{0.f, 0.f, 0.f, 0.f};
#pragma unroll
    for (int kk = 0; kk < 64; kk += 32) {
        short8 a = *(const short8*)&q_s[(wid * 16 + lr) * 72 + kk + lg * 8];
#pragma unroll
        for (int n = 0; n < 8; n++) {
            short8 bf = *(const short8*)&k_s[(n * 16 + lr) * 72 + kk + lg * 8];
            sacc[n] = __builtin_amdgcn_mfma_f32_16x16x32_bf16(a, bf, sacc[n], 0, 0, 0);
        }
    }
    // scaled-exp + causal mask + row-sums (dst = dstBase + wid*16 + lg*4 + j)
    float z[4] = {0.f, 0.f, 0.f, 0.f};
#pragma unroll
    for (int n = 0; n < 8; n++) {
        int src = n * 16 + lr;
#pragma unroll
        for (int j = 0; j < 4; j++) {
            int dst = dstBase + wid * 16 + lg * 4 + j;
            float s = sacc[n][j] * 0.125f;
            s = __expf(fminf(fmaxf(s, -10.f), 10.f));
            if (causal && src > dst) s = 0.f;
            sacc[n][j] = s;
            z[j] += s;
        }
    }
#pragma unroll
    for (int j = 0; j < 4; j++) {
        z[j] += __shfl_xor(z[j], 1); z[j] += __shfl_xor(z[j], 2);
        z[j] += __shfl_xor(z[j], 4); z[j] += __shfl_xor(z[j], 8);
    }
#pragma unroll
    for (int n = 0; n < 8; n++) {
        int src = n * 16 + lr;
#pragma unroll
        for (int j = 0; j < 4; j++)
            p_s[(wid * 16 + lg * 4 + j) * 136 + src] = f2bf(sacc[n][j]);
    }
    if (lr == 0) {
#pragma unroll
        for (int j = 0; j < 4; j++) z_s[wid * 16 + lg * 4 + j] = z[j];
    }
    __syncthreads();

    // ---- O^T[dk][dst] = vt @ p^T : wave computes 16 dk rows x 64 dst ----
    f32x4 oacc[4];
#pragma unroll
    for (int n = 0; n < 4; n++) oacc[n] = f32x4{0.f, 0.f, 0.f, 0.f};
#pragma unroll
    for (int kk = 0; kk < 128; kk += 32) {
        int dkr = wid * 16 + lr;
        int g = ((kk >> 3) + lg) ^ (dkr >> 3);
        short8 a = *(const short8*)&vt_s[dkr * 128 + g * 8];
#pragma unroll
        for (int n = 0; n < 4; n++) {
            short8 bf = *(const short8*)&p_s[(n * 16 + lr) * 136 + kk + lg * 8];
            oacc[n] = __builtin_amdgcn_mfma_f32_16x16x32_bf16(a, bf, oacc[n], 0, 0, 0);
        }
    }
    // write out: dk = wid*16 + lg*4 + j, dst_local = n*16 + lr
#pragma unroll
    for (int n = 0; n < 4; n++) {
        int dl = n * 16 + lr;
        float zz = z_s[dl];
#pragma unroll
        for (int j = 0; j < 4; j++) {
            int dk = wid * 16 + lg * 4 + j;
            O[qbase + (long)dl * RS + dk] = f2bf(oacc[n][j] / zz);
        }
    }
}

// ---------------------------------------------------------------------------
// In-place row log_softmax over V=32000: online max+sum (1 read) + write pass
// ---------------------------------------------------------------------------
__global__ __launch_bounds__(256) void lsm_k(float* __restrict__ X)
{
    __shared__ float rm[256], rs[256];
    int row = blockIdx.x, tid = threadIdx.x;
    f32x4* x4 = (f32x4*)(X + (long)row * cV);
    constexpr int NV = cV / 4;

    float m = -1e30f, s = 0.f;
    for (int i = tid; i < NV; i += 256) {
        f32x4 v = x4[i];
        float cm = fmaxf(fmaxf(v[0], v[1]), fmaxf(v[2], v[3]));
        float nm = fmaxf(m, cm);
        s = s * __expf(m - nm)
          + __expf(v[0] - nm) + __expf(v[1] - nm)
          + __expf(v[2] - nm) + __expf(v[3] - nm);
        m = nm;
    }
    rm[tid] = m; rs[tid] = s;
    __syncthreads();
    for (int st = 128; st > 0; st >>= 1) {
        if (tid < st) {
            float m2 = rm[tid + st], s2 = rs[tid + st];
            float nm = fmaxf(rm[tid], m2);
            rs[tid] = rs[tid] * __expf(rm[tid] - nm) + s2 * __expf(m2 - nm);
            rm[tid] = nm;
        }
        __syncthreads();
    }
    float lse = rm[0] + __logf(rs[0]);

    for (int i = tid; i < NV; i += 256) {
        f32x4 v = x4[i];
        v[0] -= lse; v[1] -= lse; v[2] -= lse; v[3] -= lse;
        x4[i] = v;
    }
}

// ---------------------------------------------------------------------------
extern "C" void kernel_launch(void* const* d_in, const int* in_sizes, int n_in,
                              void* d_out, int out_size, void* d_ws, size_t ws_size,
                              hipStream_t stream)
{
    const float* src_emb  = (const float*)d_in[0];
    const float* tgt_emb  = (const float*)d_in[1];
    const float* enc_Wqkv = (const float*)d_in[2];
    const float* enc_Wo   = (const float*)d_in[3];
    const float* enc_ln1  = (const float*)d_in[4];
    const float* enc_W1   = (const float*)d_in[5];
    const float* enc_b1   = (const float*)d_in[6];
    const float* enc_W2   = (const float*)d_in[7];
    const float* enc_b2   = (const float*)d_in[8];
    const float* enc_ln2  = (const float*)d_in[9];
    const float* enc_lnf  = (const float*)d_in[10];
    const float* dec_Wqkv = (const float*)d_in[11];
    const float* dec_Wo   = (const float*)d_in[12];
    const float* dec_ln1  = (const float*)d_in[13];
    const float* dec_cWq  = (const float*)d_in[14];
    const float* dec_cWkv = (const float*)d_in[15];
    const float* dec_cWo  = (const float*)d_in[16];
    const float* dec_ln2  = (const float*)d_in[17];
    const float* dec_W1   = (const float*)d_in[18];
    const float* dec_b1   = (const float*)d_in[19];
    const float* dec_W2   = (const float*)d_in[20];
    const float* dec_b2   = (const float*)d_in[21];
    const float* dec_ln3  = (const float*)d_in[22];
    const float* dec_lnf  = (const float*)d_in[23];
    const float* gen_W    = (const float*)d_in[24];
    const float* gen_b    = (const float*)d_in[25];
    const int* src_tok    = (const int*)d_in[26];
    const int* tgt_tok    = (const int*)d_in[27];
    // edge lists (28..33): fixed structure (full / causal) -> unused

    const long ND = (long)cN * cD;          // 262144
    const long DD = (long)cD * cD;          // 262144
    const long DF = (long)cD * cF;          // 1048576

    // fp32 region
    float* x_e = (float*)d_ws;
    float* x_d = x_e + ND;

    // bf16 region
    short* qkvb  = (short*)(x_d + ND);      // [3][N,D]  q,k,v
    short* ob_bf = qkvb + 3 * ND;           // [N,D]
    short* hb_bf = ob_bf + ND;              // [N,F]
    short* kvc   = hb_bf + (long)cN * cF;   // [4][N,D] cross K/V (l0k,l0v,l1k,l1v)
    short* xn_bf = kvc + 4 * ND;            // [N,D]
    // transposed bf16 weights
    short* wDD  = xn_bf + ND;               // 24 x [D][D]
    short* wDF  = wDD + 24 * DD;            // 4  x [F][D]  (W1 slices)
    short* wFD  = wDF + 4 * DF;             // 4  x [D][F]  (W2 slices)
    short* genT = wFD + 4 * DF;             // [V][D]

    // DD slice order: 0-5 enc_Wqkv | 6-7 enc_Wo | 8-13 dec_Wqkv | 14-15 dec_Wo
    //                 16-17 dec_cWq | 18-21 dec_cWkv | 22-23 dec_cWo
    {
        TCP p{};
        int i = 0;
        for (int j = 0; j < 6; j++) p.s[i++] = enc_Wqkv + (long)j * DD;
        for (int j = 0; j < 2; j++) p.s[i++] = enc_Wo   + (long)j * DD;
        for (int j = 0; j < 6; j++) p.s[i++] = dec_Wqkv + (long)j * DD;
        for (int j = 0; j < 2; j++) p.s[i++] = dec_Wo   + (long)j * DD;
        for (int j = 0; j < 2; j++) p.s[i++] = dec_cWq  + (long)j * DD;
        for (int j = 0; j < 4; j++) p.s[i++] = dec_cWkv + (long)j * DD;
        for (int j = 0; j < 2; j++) p.s[i++] = dec_cWo  + (long)j * DD;
        tconv_k<<<dim3(cD / 64, cD / 64, 24), 256, 0, stream>>>(p, wDD, cD, cD);
    }
    {
        TCP p{};
        p.s[0] = enc_W1; p.s[1] = enc_W1 + DF; p.s[2] = dec_W1; p.s[3] = dec_W1 + DF;
        tconv_k<<<dim3(cF / 64, cD / 64, 4), 256, 0, stream>>>(p, wDF, cD, cF);
    }
    {
        TCP p{};
        p.s[0] = enc_W2; p.s[1] = enc_W2 + DF; p.s[2] = dec_W2; p.s[3] = dec_W2 + DF;
        tconv_k<<<dim3(cD / 64, cF / 64, 4), 256, 0, stream>>>(p, wFD, cF, cD);
    }
    {
        TCP p{};
        p.s[0] = gen_W;
        tconv_k<<<dim3(cV / 64, cD / 64, 1), 256, 0, stream>>>(p, genT, cD, cV);
    }

    embed_k<<<cN, 256, 0, stream>>>(src_emb, src_tok, x_e);
    embed_k<<<cN, 256, 0, stream>>>(tgt_emb, tgt_tok, x_d);

    dim3 gDD11(cD / 32, cN / 32);            // <1,1>: 256 blocks
    dim3 gFFN1(cF / 64, cN / 64);            // <2,2>: 256 blocks
    dim3 gAttn(cH, cB, 2);                   // 64 blocks

    // ---- encoder ----
    for (int l = 0; l < cL; l++) {
        gemm_k<1, 1, true><<<dim3(cD / 32, cN / 32, 3), 256, 0, stream>>>(
            nullptr, x_e, enc_ln1 + (long)(2 * l) * cD, enc_ln1 + (long)(2 * l + 1) * cD,
            wDD + (long)(3 * l) * DD, nullptr, nullptr, nullptr, qkvb,
            cD, cD, 0, DD, ND, 0);
        attn_k<<<gAttn, 256, 0, stream>>>(qkvb, qkvb + ND, qkvb + 2 * ND, ob_bf, 0);
        gemm_k<1, 1, false><<<gDD11, 256, 0, stream>>>(
            ob_bf, nullptr, nullptr, nullptr, wDD + (long)(6 + l) * DD,
            nullptr, x_e, x_e, nullptr, cD, cD, 0, 0, 0, 0);
        gemm_k<2, 2, true><<<gFFN1, 256, 0, stream>>>(
            nullptr, x_e, enc_ln2 + (long)(2 * l) * cD, enc_ln2 + (long)(2 * l + 1) * cD,
            wDF + (long)l * DF, enc_b1 + (long)l * cF, nullptr, nullptr, hb_bf,
            cF, cD, 1, 0, 0, 0);
        gemm_k<1, 1, false><<<gDD11, 256, 0, stream>>>(
            hb_bf, nullptr, nullptr, nullptr, wFD + (long)l * DF,
            enc_b2 + (long)l * cD, x_e, x_e, nullptr, cD, cF, 0, 0, 0, 0);
    }

    // ---- cross K/V for both decoder layers (enc_lnf fused), z=4 ----
    gemm_k<1, 1, true><<<dim3(cD / 32, cN / 32, 4), 256, 0, stream>>>(
        nullptr, x_e, enc_lnf, enc_lnf + cD,
        wDD + 18 * DD, nullptr, nullptr, nullptr, kvc,
        cD, cD, 0, DD, ND, 0);

    // ---- decoder ----
    for (int l = 0; l < cL; l++) {
        gemm_k<1, 1, true><<<dim3(cD / 32, cN / 32, 3), 256, 0, stream>>>(
            nullptr, x_d, dec_ln1 + (long)(2 * l) * cD, dec_ln1 + (long)(2 * l + 1) * cD,
            wDD + (long)(8 + 3 * l) * DD, nullptr, nullptr, nullptr, qkvb,
            cD, cD, 0, DD, ND, 0);
        attn_k<<<gAttn, 256, 0, stream>>>(qkvb, qkvb + ND, qkvb + 2 * ND, ob_bf, 1);
        gemm_k<1, 1, false><<<gDD11, 256, 0, stream>>>(
            ob_bf, nullptr, nullptr, nullptr, wDD + (long)(14 + l) * DD,
            nullptr, x_d, x_d, nullptr, cD, cD, 0, 0, 0, 0);

        gemm_k<1, 1, true><<<gDD11, 256, 0, stream>>>(
            nullptr, x_d, dec_ln2 + (long)(2 * l) * cD, dec_ln2 + (long)(2 * l + 1) * cD,
            wDD + (long)(16 + l) * DD, nullptr, nullptr, nullptr, qkvb,
            cD, cD, 0, 0, 0, 0);
        attn_k<<<gAttn, 256, 0, stream>>>(qkvb, kvc + (long)(2 * l) * ND,
                                          kvc + (long)(2 * l + 1) * ND, ob_bf, 0);
        gemm_k<1, 1, false><<<gDD11, 256, 0, stream>>>(
            ob_bf, nullptr, nullptr, nullptr, wDD + (long)(22 + l) * DD,
            nullptr, x_d, x_d, nullptr, cD, cD, 0, 0, 0, 0);

        gemm_k<2, 2, true><<<gFFN1, 256, 0, stream>>>(
            nullptr, x_d, dec_ln3 + (long)(2 * l) * cD, dec_ln3 + (long)(2 * l + 1) * cD,
            wDF + (long)(2 + l) * DF, dec_b1 + (long)l * cF, nullptr, nullptr, hb_bf,
            cF, cD, 1, 0, 0, 0);
        gemm_k<1, 1, false><<<gDD11, 256, 0, stream>>>(
            hb_bf, nullptr, nullptr, nullptr, wFD + (long)(2 + l) * DF,
            dec_b2 + (long)l * cD, x_d, x_d, nullptr, cD, cF, 0, 0, 0, 0);
    }

    // ---- final LN + generator + log_softmax ----
    ln_k<<<cN, 256, 0, stream>>>(x_d, dec_lnf, dec_lnf + cD, xn_bf);
    gemm_k<4, 2, false><<<dim3(cV / 64, cN / 128), 256, 0, stream>>>(
        xn_bf, nullptr, nullptr, nullptr, genT, gen_b, nullptr,
        (float*)d_out, nullptr, cV, cD, 0, 0, 0, 1);
    lsm_k<<<cN, 256, 0, stream>>>((float*)d_out);
}